// Round 6
// baseline (553.868 us; speedup 1.0000x reference)
//
#include <hip/hip_runtime.h>

#define N_NODES 50000
#define N_EDGES 600000
#define DIM 128
#define NB 782                 // 64-node buckets; also the hist/scatter block partition
#define EPB 768                // edges per partition block: 782*768 = 600576 >= 600000
#define ACC_S 132              // LDS accumulator stride (floats): bank=(132/4*r+l)%32=(r+l)%32, 16B-aligned

typedef short bf16x8 __attribute__((ext_vector_type(8)));
typedef float f32x4 __attribute__((ext_vector_type(4)));

__device__ __forceinline__ float bf2f(unsigned short u) {
    union { unsigned int i; float f; } x; x.i = ((unsigned int)u) << 16; return x.f;
}
__device__ __forceinline__ unsigned short f2bf(float f) {
    union { float f; unsigned int i; } x; x.f = f;
    unsigned int r = x.i + 0x7FFFu + ((x.i >> 16) & 1u);   // RNE
    return (unsigned short)(r >> 16);
}

// ---------------- MFMA GEMM + fused bucket histogram ----------------
// h[n][d] = bf16( sum_k x[n][k] * W[d][k] ), fp32 MFMA accumulate.
// Histogram: block j counts its EPB edges per 64-node bucket in LDS, then one
// coalesced 3KB row write H[j][*]. Zero global atomics; hides under MFMA.
#define GEMM_BLOCKS NB           // ceil(50000/64) == 782 == NB

__global__ __launch_bounds__(256) void gemm_kernel(const float* __restrict__ x,
                                                   const float* __restrict__ W,
                                                   unsigned short* __restrict__ h,
                                                   const int* __restrict__ rows,
                                                   int* __restrict__ Hm) {
    __shared__ unsigned char Wl[128 * 256];   // bf16[128 dims][128 k], swizzled
    __shared__ int cntL[NB];
    const int tid = threadIdx.x;

    // ---- zero bucket counters
    if (Hm) {
        for (int i = tid; i < NB; i += 256) cntL[i] = 0;
    }

    // ---- stage W -> LDS bf16 (swizzled): 4096 float4 chunks, 16 per thread
#pragma unroll
    for (int i = 0; i < 16; ++i) {
        int c  = tid + i * 256;
        int od = c >> 5;                 // out dim (W row)
        int kg = c & 31;                 // float4 group: k0 = kg*4
        float4 w = *((const float4*)(W + od * DIM) + kg);
        unsigned int lo = (unsigned int)f2bf(w.x) | ((unsigned int)f2bf(w.y) << 16);
        unsigned int hi = (unsigned int)f2bf(w.z) | ((unsigned int)f2bf(w.w) << 16);
        int byte = od * 256 + ((kg * 8) ^ ((od & 7) << 4));
        *reinterpret_cast<uint2*>(Wl + byte) = make_uint2(lo, hi);
    }

    // ---- load + convert this wave's x rows (node = lane&15, k-slot = lane>>4)
    const int lane = tid & 63;
    const int wv   = tid >> 6;
    const int q    = lane >> 4;
    const int node = blockIdx.x * 64 + wv * 16 + (lane & 15);
    const int ncl  = node < N_NODES ? node : N_NODES - 1;

    bf16x8 xb[4];
#pragma unroll
    for (int s = 0; s < 4; ++s) {
        const float* xp = x + (size_t)ncl * DIM + s * 32 + q * 8;
        float4 x0 = *(const float4*)(xp);
        float4 x1 = *(const float4*)(xp + 4);
        bf16x8 v;
        v[0] = (short)f2bf(x0.x); v[1] = (short)f2bf(x0.y);
        v[2] = (short)f2bf(x0.z); v[3] = (short)f2bf(x0.w);
        v[4] = (short)f2bf(x1.x); v[5] = (short)f2bf(x1.y);
        v[6] = (short)f2bf(x1.z); v[7] = (short)f2bf(x1.w);
        xb[s] = v;
    }

    __syncthreads();   // cntL zeroed + W staged

    // ---- fused histogram: LDS atomics only
    if (Hm) {
        int ebase = blockIdx.x * EPB;
#pragma unroll
        for (int i = 0; i < 3; ++i) {
            int e = ebase + tid + i * 256;
            if (e < N_EDGES) atomicAdd(&cntL[rows[e] >> 6], 1);
        }
    }

    // ---- 8 dim-tiles x 4 k-steps of mfma_f32_16x16x32_bf16
#pragma unroll
    for (int dt = 0; dt < 8; ++dt) {
        f32x4 acc = {0.f, 0.f, 0.f, 0.f};
        const int od = dt * 16 + (lane & 15);
#pragma unroll
        for (int s = 0; s < 4; ++s) {
            int byte = od * 256 + ((s * 64 + q * 16) ^ ((od & 7) << 4));
            bf16x8 a = *reinterpret_cast<const bf16x8*>(Wl + byte);
            acc = __builtin_amdgcn_mfma_f32_16x16x32_bf16(a, xb[s], acc, 0, 0, 0);
        }
        if (node < N_NODES) {
            unsigned int lo = (unsigned int)f2bf(acc[0]) | ((unsigned int)f2bf(acc[1]) << 16);
            unsigned int hi = (unsigned int)f2bf(acc[2]) | ((unsigned int)f2bf(acc[3]) << 16);
            *reinterpret_cast<uint2*>(h + (size_t)node * DIM + dt * 16 + q * 4) = make_uint2(lo, hi);
        }
    }

    if (Hm) {
        __syncthreads();   // all histogram atomics done
        int* Hrow = Hm + (size_t)blockIdx.x * NB;
        for (int i = tid; i < NB; i += 256) Hrow[i] = cntL[i];   // coalesced 3KB
    }
}

// ---------------- scanA: per-bucket exclusive scan of H[j][b] along j ----------------
// One wave per bucket. In-place: H[j][b] <- sum_{j'<j} H[j'][b]; tot[b] = column total.
__global__ __launch_bounds__(256) void scanA_kernel(int* __restrict__ Hm,
                                                    int* __restrict__ tot) {
    int gw   = (blockIdx.x * 256 + threadIdx.x) >> 6;   // bucket
    int lane = threadIdx.x & 63;
    if (gw >= NB) return;
    int carry = 0;
    for (int ch = 0; ch < 13; ++ch) {
        int j = ch * 64 + lane;
        int v = (j < NB) ? Hm[(size_t)j * NB + gw] : 0;
        int incl = v;
#pragma unroll
        for (int d = 1; d < 64; d <<= 1) {
            int t = __shfl_up(incl, d);
            if (lane >= d) incl += t;
        }
        if (j < NB) Hm[(size_t)j * NB + gw] = carry + incl - v;
        carry += __shfl(incl, 63);
    }
    if (lane == 0) tot[gw] = carry;
}

// ---------------- scanB: exclusive scan of bucket totals -> boff ----------------
__global__ __launch_bounds__(1024) void scanB_kernel(const int* __restrict__ tot,
                                                     int* __restrict__ boff) {
    __shared__ int s[1024];
    int t = threadIdx.x;
    int v = (t < NB) ? tot[t] : 0;
    s[t] = v;
    __syncthreads();
    for (int d = 1; d < 1024; d <<= 1) {
        int a = (t >= d) ? s[t - d] : 0;
        __syncthreads();
        s[t] += a;
        __syncthreads();
    }
    if (t < NB) boff[t] = s[t] - v;
    if (t == 0) boff[NB] = N_EDGES;
}

// ---------------- scatter: deterministic bucket partition, LDS cursors ----------------
// Block j seeds cursors = boff[b] + H[j][b]; slots via LDS atomicAdd; writes are
// per-(block,bucket) contiguous chunks. Record: {col | row_rel<<16, val fp32}.
__global__ __launch_bounds__(256) void scatter_kernel(const int* __restrict__ rows,
                                                      const int* __restrict__ cols,
                                                      const float* __restrict__ vals,
                                                      const int* __restrict__ Hm,
                                                      const int* __restrict__ boff,
                                                      int2* __restrict__ erec) {
    __shared__ int cl[NB];
    int tid = threadIdx.x, j = blockIdx.x;
    const int* Hrow = Hm + (size_t)j * NB;
    for (int i = tid; i < NB; i += 256) cl[i] = boff[i] + Hrow[i];
    __syncthreads();
    int ebase = j * EPB;
#pragma unroll
    for (int i = 0; i < 3; ++i) {
        int e = ebase + tid + i * 256;
        if (e < N_EDGES) {
            int r = rows[e];
            int slot = atomicAdd(&cl[r >> 6], 1);
            int2 rec;
            rec.x = cols[e] | ((r & 63) << 16);
            rec.y = __float_as_int(vals[e]);
            erec[slot] = rec;
        }
    }
}

// ---------------- gather: one block per 64-node bucket, LDS fp32 accumulate ----------------
// Edge-parallel: each wave takes a quarter of the bucket's edges; lane owns dims
// {l, l+64}; ds_add_f32 at bank (r+l)%32 -> 2-way aliasing (free). Fused ReLU.
__global__ __launch_bounds__(256) void gather_kernel(const unsigned short* __restrict__ h,
                                                     const int2* __restrict__ erec,
                                                     const int* __restrict__ boff,
                                                     float* __restrict__ out) {
    __shared__ float acc[64 * ACC_S];
    int tid = threadIdx.x, b = blockIdx.x;
    for (int i = tid; i < 64 * ACC_S; i += 256) acc[i] = 0.f;
    __syncthreads();

    int beg = boff[b], end = boff[b + 1];
    int cnt = end - beg;
    int w = tid >> 6, lane = tid & 63;
    int qb = beg + (cnt * w) / 4;
    int qe = beg + (cnt * (w + 1)) / 4;

    int i = qb;
    for (; i + 4 <= qe; i += 4) {
        int2 r0 = erec[i], r1 = erec[i + 1], r2 = erec[i + 2], r3 = erec[i + 3];
        int c0 = r0.x & 0xFFFF, c1 = r1.x & 0xFFFF, c2 = r2.x & 0xFFFF, c3 = r3.x & 0xFFFF;
        unsigned short a0 = h[(size_t)c0 * DIM + lane],      b0 = h[(size_t)c0 * DIM + 64 + lane];
        unsigned short a1 = h[(size_t)c1 * DIM + lane],      b1 = h[(size_t)c1 * DIM + 64 + lane];
        unsigned short a2 = h[(size_t)c2 * DIM + lane],      b2 = h[(size_t)c2 * DIM + 64 + lane];
        unsigned short a3 = h[(size_t)c3 * DIM + lane],      b3 = h[(size_t)c3 * DIM + 64 + lane];
        float v0 = __int_as_float(r0.y), v1 = __int_as_float(r1.y);
        float v2 = __int_as_float(r2.y), v3 = __int_as_float(r3.y);
        int rr0 = (r0.x >> 16) * ACC_S, rr1 = (r1.x >> 16) * ACC_S;
        int rr2 = (r2.x >> 16) * ACC_S, rr3 = (r3.x >> 16) * ACC_S;
        atomicAdd(&acc[rr0 + lane],      v0 * bf2f(a0));
        atomicAdd(&acc[rr0 + 64 + lane], v0 * bf2f(b0));
        atomicAdd(&acc[rr1 + lane],      v1 * bf2f(a1));
        atomicAdd(&acc[rr1 + 64 + lane], v1 * bf2f(b1));
        atomicAdd(&acc[rr2 + lane],      v2 * bf2f(a2));
        atomicAdd(&acc[rr2 + 64 + lane], v2 * bf2f(b2));
        atomicAdd(&acc[rr3 + lane],      v3 * bf2f(a3));
        atomicAdd(&acc[rr3 + 64 + lane], v3 * bf2f(b3));
    }
    for (; i < qe; ++i) {
        int2 r0 = erec[i];
        int c0 = r0.x & 0xFFFF;
        unsigned short a0 = h[(size_t)c0 * DIM + lane], b0 = h[(size_t)c0 * DIM + 64 + lane];
        float v0 = __int_as_float(r0.y);
        int rr0 = (r0.x >> 16) * ACC_S;
        atomicAdd(&acc[rr0 + lane],      v0 * bf2f(a0));
        atomicAdd(&acc[rr0 + 64 + lane], v0 * bf2f(b0));
    }
    __syncthreads();

    // ---- write out + ReLU: 64 nodes x 32 float4, coalesced
    int base = b * 64;
    for (int k = tid; k < 64 * 32; k += 256) {
        int n = k >> 5, f4 = k & 31;
        if (base + n < N_NODES) {
            const float* ap = &acc[n * ACC_S + f4 * 4];
            float4 v;
            v.x = fmaxf(ap[0], 0.f);
            v.y = fmaxf(ap[1], 0.f);
            v.z = fmaxf(ap[2], 0.f);
            v.w = fmaxf(ap[3], 0.f);
            *reinterpret_cast<float4*>(&out[(size_t)(base + n) * DIM + f4 * 4]) = v;
        }
    }
}

// ---------------- fallback: atomic scatter over bf16 h ----------------
__global__ __launch_bounds__(256) void edge_kernel(const unsigned short* __restrict__ h,
                                                   const float* __restrict__ vals,
                                                   const int* __restrict__ rows,
                                                   const int* __restrict__ cols,
                                                   float* __restrict__ out) {
    long long gid = (long long)blockIdx.x * 256 + threadIdx.x;
    int e    = (int)(gid >> 5);
    int lane = (int)(gid & 31);
    if (e >= N_EDGES) return;
    int r = rows[e];
    int c = cols[e];
    float v = vals[e];
    ushort4 hv = *((const ushort4*)(h + (size_t)c * DIM) + lane);
    float* op = &out[(size_t)r * DIM + lane * 4];
    atomicAdd(op + 0, v * bf2f(hv.x));
    atomicAdd(op + 1, v * bf2f(hv.y));
    atomicAdd(op + 2, v * bf2f(hv.z));
    atomicAdd(op + 3, v * bf2f(hv.w));
}

__global__ __launch_bounds__(256) void relu_kernel(float* __restrict__ out) {
    int i = blockIdx.x * 256 + threadIdx.x;
    float4* p = reinterpret_cast<float4*>(out) + i;
    float4 v = *p;
    v.x = fmaxf(v.x, 0.f);
    v.y = fmaxf(v.y, 0.f);
    v.z = fmaxf(v.z, 0.f);
    v.w = fmaxf(v.w, 0.f);
    *p = v;
}

extern "C" void kernel_launch(void* const* d_in, const int* in_sizes, int n_in,
                              void* d_out, int out_size, void* d_ws, size_t ws_size,
                              hipStream_t stream) {
    const float* x    = (const float*)d_in[0];
    const float* W    = (const float*)d_in[1];
    const float* vals = (const float*)d_in[2];
    const int*   rows = (const int*)d_in[3];
    const int*   cols = (const int*)d_in[4];
    float* out = (float*)d_out;

    // ---- workspace layout ----
    unsigned short* h = (unsigned short*)d_ws;               // 12.8 MB bf16
    int2* erec = (int2*)(h + (size_t)N_NODES * DIM);         // 4.8 MB
    int*  Hm   = (int*)(erec + N_EDGES);                     // 782*782*4 = 2.45 MB
    int*  tot  = Hm + (size_t)NB * NB;                       // 782
    int*  boff = tot + NB;                                   // 783
    size_t need = (size_t)((char*)(boff + NB + 1) - (char*)d_ws);

    if (ws_size >= need) {
        // h = bf16(x @ W^T) via MFMA, bucket histogram fused (LDS-only atomics)
        gemm_kernel<<<GEMM_BLOCKS, 256, 0, stream>>>(x, W, h, rows, Hm);
        scanA_kernel<<<(NB * 64 + 255) / 256, 256, 0, stream>>>(Hm, tot);
        scanB_kernel<<<1, 1024, 0, stream>>>(tot, boff);
        scatter_kernel<<<NB, 256, 0, stream>>>(rows, cols, vals, Hm, boff, erec);
        gather_kernel<<<NB, 256, 0, stream>>>(h, erec, boff, out);
    } else {
        // fallback: atomic scatter path (needs only h)
        gemm_kernel<<<GEMM_BLOCKS, 256, 0, stream>>>(x, W, h, nullptr, nullptr);
        hipMemsetAsync(d_out, 0, (size_t)N_NODES * DIM * sizeof(float), stream);
        edge_kernel<<<(N_EDGES * 32) / 256, 256, 0, stream>>>(h, vals, rows, cols, out);
        relu_kernel<<<(N_NODES * DIM / 4) / 256, 256, 0, stream>>>(out);
    }
}

// Round 7
// 80.746 us; speedup vs baseline: 6.8594x; 6.8594x over previous
//
#include <hip/hip_runtime.h>

#define N_NODES 50000
#define N_EDGES 600000
#define DIM 128
#define NB 782                 // 64-node buckets; also the hist/scatter block partition
#define EPB 768                // edges per partition block: 782*768 = 600576 >= 600000
#define GCAP 2048              // gather LDS sort capacity (mean 767, sd 28 -> 27 sigma)

typedef short bf16x8 __attribute__((ext_vector_type(8)));
typedef float f32x4 __attribute__((ext_vector_type(4)));

__device__ __forceinline__ float bf2f(unsigned short u) {
    union { unsigned int i; float f; } x; x.i = ((unsigned int)u) << 16; return x.f;
}
__device__ __forceinline__ unsigned short f2bf(float f) {
    union { float f; unsigned int i; } x; x.f = f;
    unsigned int r = x.i + 0x7FFFu + ((x.i >> 16) & 1u);   // RNE
    return (unsigned short)(r >> 16);
}

// ---------------- MFMA GEMM + fused bucket histogram ----------------
#define GEMM_BLOCKS NB           // ceil(50000/64) == 782 == NB

__global__ __launch_bounds__(256) void gemm_kernel(const float* __restrict__ x,
                                                   const float* __restrict__ W,
                                                   unsigned short* __restrict__ h,
                                                   const int* __restrict__ rows,
                                                   int* __restrict__ Hm) {
    __shared__ unsigned char Wl[128 * 256];   // bf16[128 dims][128 k], swizzled
    __shared__ int cntL[NB];
    const int tid = threadIdx.x;

    if (Hm) {
        for (int i = tid; i < NB; i += 256) cntL[i] = 0;
    }

    // ---- stage W -> LDS bf16 (swizzled)
#pragma unroll
    for (int i = 0; i < 16; ++i) {
        int c  = tid + i * 256;
        int od = c >> 5;
        int kg = c & 31;
        float4 w = *((const float4*)(W + od * DIM) + kg);
        unsigned int lo = (unsigned int)f2bf(w.x) | ((unsigned int)f2bf(w.y) << 16);
        unsigned int hi = (unsigned int)f2bf(w.z) | ((unsigned int)f2bf(w.w) << 16);
        int byte = od * 256 + ((kg * 8) ^ ((od & 7) << 4));
        *reinterpret_cast<uint2*>(Wl + byte) = make_uint2(lo, hi);
    }

    // ---- load + convert this wave's x rows (node = lane&15, k-slot = lane>>4)
    const int lane = tid & 63;
    const int wv   = tid >> 6;
    const int q    = lane >> 4;
    const int node = blockIdx.x * 64 + wv * 16 + (lane & 15);
    const int ncl  = node < N_NODES ? node : N_NODES - 1;

    bf16x8 xb[4];
#pragma unroll
    for (int s = 0; s < 4; ++s) {
        const float* xp = x + (size_t)ncl * DIM + s * 32 + q * 8;
        float4 x0 = *(const float4*)(xp);
        float4 x1 = *(const float4*)(xp + 4);
        bf16x8 v;
        v[0] = (short)f2bf(x0.x); v[1] = (short)f2bf(x0.y);
        v[2] = (short)f2bf(x0.z); v[3] = (short)f2bf(x0.w);
        v[4] = (short)f2bf(x1.x); v[5] = (short)f2bf(x1.y);
        v[6] = (short)f2bf(x1.z); v[7] = (short)f2bf(x1.w);
        xb[s] = v;
    }

    __syncthreads();   // cntL zeroed + W staged

    // ---- fused histogram: LDS atomics only
    if (Hm) {
        int ebase = blockIdx.x * EPB;
#pragma unroll
        for (int i = 0; i < 3; ++i) {
            int e = ebase + tid + i * 256;
            if (e < N_EDGES) atomicAdd(&cntL[rows[e] >> 6], 1);
        }
    }

    // ---- 8 dim-tiles x 4 k-steps of mfma_f32_16x16x32_bf16
#pragma unroll
    for (int dt = 0; dt < 8; ++dt) {
        f32x4 acc = {0.f, 0.f, 0.f, 0.f};
        const int od = dt * 16 + (lane & 15);
#pragma unroll
        for (int s = 0; s < 4; ++s) {
            int byte = od * 256 + ((s * 64 + q * 16) ^ ((od & 7) << 4));
            bf16x8 a = *reinterpret_cast<const bf16x8*>(Wl + byte);
            acc = __builtin_amdgcn_mfma_f32_16x16x32_bf16(a, xb[s], acc, 0, 0, 0);
        }
        if (node < N_NODES) {
            unsigned int lo = (unsigned int)f2bf(acc[0]) | ((unsigned int)f2bf(acc[1]) << 16);
            unsigned int hi = (unsigned int)f2bf(acc[2]) | ((unsigned int)f2bf(acc[3]) << 16);
            *reinterpret_cast<uint2*>(h + (size_t)node * DIM + dt * 16 + q * 4) = make_uint2(lo, hi);
        }
    }

    if (Hm) {
        __syncthreads();
        int* Hrow = Hm + (size_t)blockIdx.x * NB;
        for (int i = tid; i < NB; i += 256) Hrow[i] = cntL[i];   // coalesced 3KB
    }
}

// ---------------- scanA: per-bucket exclusive scan of H[j][b] along j ----------------
__global__ __launch_bounds__(256) void scanA_kernel(int* __restrict__ Hm,
                                                    int* __restrict__ tot) {
    int gw   = (blockIdx.x * 256 + threadIdx.x) >> 6;   // bucket
    int lane = threadIdx.x & 63;
    if (gw >= NB) return;
    int carry = 0;
    for (int ch = 0; ch < 13; ++ch) {
        int j = ch * 64 + lane;
        int v = (j < NB) ? Hm[(size_t)j * NB + gw] : 0;
        int incl = v;
#pragma unroll
        for (int d = 1; d < 64; d <<= 1) {
            int t = __shfl_up(incl, d);
            if (lane >= d) incl += t;
        }
        if (j < NB) Hm[(size_t)j * NB + gw] = carry + incl - v;
        carry += __shfl(incl, 63);
    }
    if (lane == 0) tot[gw] = carry;
}

// ---------------- scanB: exclusive scan of bucket totals -> boff ----------------
__global__ __launch_bounds__(1024) void scanB_kernel(const int* __restrict__ tot,
                                                     int* __restrict__ boff) {
    __shared__ int s[1024];
    int t = threadIdx.x;
    int v = (t < NB) ? tot[t] : 0;
    s[t] = v;
    __syncthreads();
    for (int d = 1; d < 1024; d <<= 1) {
        int a = (t >= d) ? s[t - d] : 0;
        __syncthreads();
        s[t] += a;
        __syncthreads();
    }
    if (t < NB) boff[t] = s[t] - v;
    if (t == 0) boff[NB] = N_EDGES;
}

// ---------------- scatter: deterministic bucket partition, LDS cursors ----------------
__global__ __launch_bounds__(256) void scatter_kernel(const int* __restrict__ rows,
                                                      const int* __restrict__ cols,
                                                      const float* __restrict__ vals,
                                                      const int* __restrict__ Hm,
                                                      const int* __restrict__ boff,
                                                      int2* __restrict__ erec) {
    __shared__ int cl[NB];
    int tid = threadIdx.x, j = blockIdx.x;
    const int* Hrow = Hm + (size_t)j * NB;
    for (int i = tid; i < NB; i += 256) cl[i] = boff[i] + Hrow[i];
    __syncthreads();
    int ebase = j * EPB;
#pragma unroll
    for (int i = 0; i < 3; ++i) {
        int e = ebase + tid + i * 256;
        if (e < N_EDGES) {
            int r = rows[e];
            int slot = atomicAdd(&cl[r >> 6], 1);
            int2 rec;
            rec.x = cols[e] | ((r & 63) << 16);
            rec.y = __float_as_int(vals[e]);
            erec[slot] = rec;
        }
    }
}

// ---------------- gather: block per bucket; LDS counting sort, REGISTER accumulate ----------------
__global__ __launch_bounds__(256) void gather_kernel(const unsigned short* __restrict__ h,
                                                     const int2* __restrict__ erec,
                                                     const int* __restrict__ boff,
                                                     float* __restrict__ out) {
    __shared__ int2 srt[GCAP];            // 16 KB sorted records
    __shared__ int hist[64];
    __shared__ int cursor[64];
    __shared__ int starts[65];
    int tid = threadIdx.x, b = blockIdx.x;
    int beg = boff[b], end = boff[b + 1];
    int cnt = end - beg;
    int w = tid >> 6, lane = tid & 63;

    if (tid < 64) hist[tid] = 0;
    __syncthreads();

    if (cnt <= GCAP) {
        // ---- phase 1: stage to registers + 64-bin histogram (1 int LDS atomic/edge)
        int2 rec[8];
        int  rr[8];
#pragma unroll
        for (int k = 0; k < 8; ++k) {
            int i = tid + k * 256;
            if (i < cnt) {
                rec[k] = erec[beg + i];
                rr[k] = (rec[k].x >> 16) & 63;
                atomicAdd(&hist[rr[k]], 1);
            }
        }
        __syncthreads();
        // ---- phase 2: exclusive scan of the 64 bins (wave 0)
        if (tid < 64) {
            int v = hist[tid], incl = v;
#pragma unroll
            for (int d = 1; d < 64; d <<= 1) {
                int t = __shfl_up(incl, d);
                if (tid >= d) incl += t;
            }
            starts[tid] = incl - v;
            cursor[tid] = incl - v;
            if (tid == 63) starts[64] = incl;
        }
        __syncthreads();
        // ---- phase 3: place into sorted LDS order
#pragma unroll
        for (int k = 0; k < 8; ++k) {
            int i = tid + k * 256;
            if (i < cnt) {
                int pos = atomicAdd(&cursor[rr[k]], 1);
                srt[pos] = rec[k];
            }
        }
        __syncthreads();
        // ---- phase 4: per-node register accumulation, 16 nodes per wave
        for (int t0 = 0; t0 < 16; ++t0) {
            int t = w * 16 + t0;
            int node = b * 64 + t;
            int s0 = starts[t], s1 = starts[t + 1];
            float ax = 0.f, ay = 0.f;
            int i = s0;
            for (; i + 4 <= s1; i += 4) {
                int2 r0 = srt[i], r1 = srt[i + 1], r2 = srt[i + 2], r3 = srt[i + 3];
                ushort2 a0 = *((const ushort2*)(h + (size_t)(r0.x & 0xFFFF) * DIM) + lane);
                ushort2 a1 = *((const ushort2*)(h + (size_t)(r1.x & 0xFFFF) * DIM) + lane);
                ushort2 a2 = *((const ushort2*)(h + (size_t)(r2.x & 0xFFFF) * DIM) + lane);
                ushort2 a3 = *((const ushort2*)(h + (size_t)(r3.x & 0xFFFF) * DIM) + lane);
                float v0 = __int_as_float(r0.y), v1 = __int_as_float(r1.y);
                float v2 = __int_as_float(r2.y), v3 = __int_as_float(r3.y);
                ax += v0 * bf2f(a0.x) + v1 * bf2f(a1.x) + v2 * bf2f(a2.x) + v3 * bf2f(a3.x);
                ay += v0 * bf2f(a0.y) + v1 * bf2f(a1.y) + v2 * bf2f(a2.y) + v3 * bf2f(a3.y);
            }
            for (; i < s1; ++i) {
                int2 r0 = srt[i];
                ushort2 a0 = *((const ushort2*)(h + (size_t)(r0.x & 0xFFFF) * DIM) + lane);
                float v0 = __int_as_float(r0.y);
                ax += v0 * bf2f(a0.x);
                ay += v0 * bf2f(a0.y);
            }
            if (node < N_NODES) {
                float2 o;
                o.x = fmaxf(ax, 0.f);
                o.y = fmaxf(ay, 0.f);
                *reinterpret_cast<float2*>(&out[(size_t)node * DIM + lane * 2]) = o;
            }
        }
    } else {
        // ---- oversize-bucket fallback (statistically unreachable, kept for correctness)
        for (int t0 = 0; t0 < 16; ++t0) {
            int t = w * 16 + t0;
            int node = b * 64 + t;
            float ax = 0.f, ay = 0.f;
            for (int i = 0; i < cnt; ++i) {
                int2 r = erec[beg + i];
                if (((r.x >> 16) & 63) == t) {
                    ushort2 a = *((const ushort2*)(h + (size_t)(r.x & 0xFFFF) * DIM) + lane);
                    float v = __int_as_float(r.y);
                    ax += v * bf2f(a.x);
                    ay += v * bf2f(a.y);
                }
            }
            if (node < N_NODES) {
                float2 o;
                o.x = fmaxf(ax, 0.f);
                o.y = fmaxf(ay, 0.f);
                *reinterpret_cast<float2*>(&out[(size_t)node * DIM + lane * 2]) = o;
            }
        }
    }
}

// ---------------- fallback: atomic scatter over bf16 h ----------------
__global__ __launch_bounds__(256) void edge_kernel(const unsigned short* __restrict__ h,
                                                   const float* __restrict__ vals,
                                                   const int* __restrict__ rows,
                                                   const int* __restrict__ cols,
                                                   float* __restrict__ out) {
    long long gid = (long long)blockIdx.x * 256 + threadIdx.x;
    int e    = (int)(gid >> 5);
    int lane = (int)(gid & 31);
    if (e >= N_EDGES) return;
    int r = rows[e];
    int c = cols[e];
    float v = vals[e];
    ushort4 hv = *((const ushort4*)(h + (size_t)c * DIM) + lane);
    float* op = &out[(size_t)r * DIM + lane * 4];
    atomicAdd(op + 0, v * bf2f(hv.x));
    atomicAdd(op + 1, v * bf2f(hv.y));
    atomicAdd(op + 2, v * bf2f(hv.z));
    atomicAdd(op + 3, v * bf2f(hv.w));
}

__global__ __launch_bounds__(256) void relu_kernel(float* __restrict__ out) {
    int i = blockIdx.x * 256 + threadIdx.x;
    float4* p = reinterpret_cast<float4*>(out) + i;
    float4 v = *p;
    v.x = fmaxf(v.x, 0.f);
    v.y = fmaxf(v.y, 0.f);
    v.z = fmaxf(v.z, 0.f);
    v.w = fmaxf(v.w, 0.f);
    *p = v;
}

extern "C" void kernel_launch(void* const* d_in, const int* in_sizes, int n_in,
                              void* d_out, int out_size, void* d_ws, size_t ws_size,
                              hipStream_t stream) {
    const float* x    = (const float*)d_in[0];
    const float* W    = (const float*)d_in[1];
    const float* vals = (const float*)d_in[2];
    const int*   rows = (const int*)d_in[3];
    const int*   cols = (const int*)d_in[4];
    float* out = (float*)d_out;

    // ---- workspace layout ----
    unsigned short* h = (unsigned short*)d_ws;               // 12.8 MB bf16
    int2* erec = (int2*)(h + (size_t)N_NODES * DIM);         // 4.8 MB
    int*  Hm   = (int*)(erec + N_EDGES);                     // 2.45 MB
    int*  tot  = Hm + (size_t)NB * NB;                       // 782
    int*  boff = tot + NB;                                   // 783
    size_t need = (size_t)((char*)(boff + NB + 1) - (char*)d_ws);

    if (ws_size >= need) {
        // h = bf16(x @ W^T) via MFMA, bucket histogram fused (LDS-only atomics)
        gemm_kernel<<<GEMM_BLOCKS, 256, 0, stream>>>(x, W, h, rows, Hm);
        scanA_kernel<<<(NB * 64 + 255) / 256, 256, 0, stream>>>(Hm, tot);
        scanB_kernel<<<1, 1024, 0, stream>>>(tot, boff);
        scatter_kernel<<<NB, 256, 0, stream>>>(rows, cols, vals, Hm, boff, erec);
        gather_kernel<<<NB, 256, 0, stream>>>(h, erec, boff, out);
    } else {
        // fallback: atomic scatter path (needs only h)
        gemm_kernel<<<GEMM_BLOCKS, 256, 0, stream>>>(x, W, h, nullptr, nullptr);
        hipMemsetAsync(d_out, 0, (size_t)N_NODES * DIM * sizeof(float), stream);
        edge_kernel<<<(N_EDGES * 32) / 256, 256, 0, stream>>>(h, vals, rows, cols, out);
        relu_kernel<<<(N_NODES * DIM / 4) / 256, 256, 0, stream>>>(out);
    }
}

// Round 8
// 68.793 us; speedup vs baseline: 8.0512x; 1.1738x over previous
//
#include <hip/hip_runtime.h>

#define N_NODES 50000
#define N_EDGES 600000
#define DIM 128
#define NB 782                 // 64-node buckets; also the hist/scatter block partition
#define EPB 768                // edges per partition block: 782*768 = 600576 >= 600000
#define GCAP 2048              // gather LDS sort capacity (mean 767, sd 28 -> 27 sigma)

typedef short bf16x8 __attribute__((ext_vector_type(8)));
typedef float f32x4 __attribute__((ext_vector_type(4)));

__device__ __forceinline__ float bf2f(unsigned short u) {
    union { unsigned int i; float f; } x; x.i = ((unsigned int)u) << 16; return x.f;
}
__device__ __forceinline__ unsigned short f2bf(float f) {
    union { float f; unsigned int i; } x; x.f = f;
    unsigned int r = x.i + 0x7FFFu + ((x.i >> 16) & 1u);   // RNE
    return (unsigned short)(r >> 16);
}

// ---------------- MFMA GEMM + fused bucket histogram ----------------
#define GEMM_BLOCKS NB           // ceil(50000/64) == 782 == NB

__global__ __launch_bounds__(256) void gemm_kernel(const float* __restrict__ x,
                                                   const float* __restrict__ W,
                                                   unsigned short* __restrict__ h,
                                                   const int* __restrict__ rows,
                                                   int* __restrict__ Hm) {
    __shared__ unsigned char Wl[128 * 256];   // bf16[128 dims][128 k], swizzled
    __shared__ int cntL[NB];
    const int tid = threadIdx.x;

    if (Hm) {
        for (int i = tid; i < NB; i += 256) cntL[i] = 0;
    }

    // ---- stage W -> LDS bf16 (swizzled)
#pragma unroll
    for (int i = 0; i < 16; ++i) {
        int c  = tid + i * 256;
        int od = c >> 5;
        int kg = c & 31;
        float4 w = *((const float4*)(W + od * DIM) + kg);
        unsigned int lo = (unsigned int)f2bf(w.x) | ((unsigned int)f2bf(w.y) << 16);
        unsigned int hi = (unsigned int)f2bf(w.z) | ((unsigned int)f2bf(w.w) << 16);
        int byte = od * 256 + ((kg * 8) ^ ((od & 7) << 4));
        *reinterpret_cast<uint2*>(Wl + byte) = make_uint2(lo, hi);
    }

    // ---- load + convert this wave's x rows (node = lane&15, k-slot = lane>>4)
    const int lane = tid & 63;
    const int wv   = tid >> 6;
    const int q    = lane >> 4;
    const int node = blockIdx.x * 64 + wv * 16 + (lane & 15);
    const int ncl  = node < N_NODES ? node : N_NODES - 1;

    bf16x8 xb[4];
#pragma unroll
    for (int s = 0; s < 4; ++s) {
        const float* xp = x + (size_t)ncl * DIM + s * 32 + q * 8;
        float4 x0 = *(const float4*)(xp);
        float4 x1 = *(const float4*)(xp + 4);
        bf16x8 v;
        v[0] = (short)f2bf(x0.x); v[1] = (short)f2bf(x0.y);
        v[2] = (short)f2bf(x0.z); v[3] = (short)f2bf(x0.w);
        v[4] = (short)f2bf(x1.x); v[5] = (short)f2bf(x1.y);
        v[6] = (short)f2bf(x1.z); v[7] = (short)f2bf(x1.w);
        xb[s] = v;
    }

    __syncthreads();   // cntL zeroed + W staged

    // ---- fused histogram: LDS atomics only
    if (Hm) {
        int ebase = blockIdx.x * EPB;
#pragma unroll
        for (int i = 0; i < 3; ++i) {
            int e = ebase + tid + i * 256;
            if (e < N_EDGES) atomicAdd(&cntL[rows[e] >> 6], 1);
        }
    }

    // ---- 8 dim-tiles x 4 k-steps of mfma_f32_16x16x32_bf16
#pragma unroll
    for (int dt = 0; dt < 8; ++dt) {
        f32x4 acc = {0.f, 0.f, 0.f, 0.f};
        const int od = dt * 16 + (lane & 15);
#pragma unroll
        for (int s = 0; s < 4; ++s) {
            int byte = od * 256 + ((s * 64 + q * 16) ^ ((od & 7) << 4));
            bf16x8 a = *reinterpret_cast<const bf16x8*>(Wl + byte);
            acc = __builtin_amdgcn_mfma_f32_16x16x32_bf16(a, xb[s], acc, 0, 0, 0);
        }
        if (node < N_NODES) {
            unsigned int lo = (unsigned int)f2bf(acc[0]) | ((unsigned int)f2bf(acc[1]) << 16);
            unsigned int hi = (unsigned int)f2bf(acc[2]) | ((unsigned int)f2bf(acc[3]) << 16);
            *reinterpret_cast<uint2*>(h + (size_t)node * DIM + dt * 16 + q * 4) = make_uint2(lo, hi);
        }
    }

    if (Hm) {
        __syncthreads();
        int* Hrow = Hm + (size_t)blockIdx.x * NB;
        for (int i = tid; i < NB; i += 256) Hrow[i] = cntL[i];   // coalesced 3KB
    }
}

// ---------------- scanA: per-bucket exclusive scan of H[j][b] along j ----------------
__global__ __launch_bounds__(256) void scanA_kernel(int* __restrict__ Hm,
                                                    int* __restrict__ tot) {
    int gw   = (blockIdx.x * 256 + threadIdx.x) >> 6;   // bucket
    int lane = threadIdx.x & 63;
    if (gw >= NB) return;
    int carry = 0;
    for (int ch = 0; ch < 13; ++ch) {
        int j = ch * 64 + lane;
        int v = (j < NB) ? Hm[(size_t)j * NB + gw] : 0;
        int incl = v;
#pragma unroll
        for (int d = 1; d < 64; d <<= 1) {
            int t = __shfl_up(incl, d);
            if (lane >= d) incl += t;
        }
        if (j < NB) Hm[(size_t)j * NB + gw] = carry + incl - v;
        carry += __shfl(incl, 63);
    }
    if (lane == 0) tot[gw] = carry;
}

// ---------------- scanB: exclusive scan of bucket totals -> boff ----------------
__global__ __launch_bounds__(1024) void scanB_kernel(const int* __restrict__ tot,
                                                     int* __restrict__ boff) {
    __shared__ int s[1024];
    int t = threadIdx.x;
    int v = (t < NB) ? tot[t] : 0;
    s[t] = v;
    __syncthreads();
    for (int d = 1; d < 1024; d <<= 1) {
        int a = (t >= d) ? s[t - d] : 0;
        __syncthreads();
        s[t] += a;
        __syncthreads();
    }
    if (t < NB) boff[t] = s[t] - v;
    if (t == 0) boff[NB] = N_EDGES;
}

// ---------------- scatter: deterministic bucket partition, LDS cursors ----------------
__global__ __launch_bounds__(256) void scatter_kernel(const int* __restrict__ rows,
                                                      const int* __restrict__ cols,
                                                      const float* __restrict__ vals,
                                                      const int* __restrict__ Hm,
                                                      const int* __restrict__ boff,
                                                      int2* __restrict__ erec) {
    __shared__ int cl[NB];
    int tid = threadIdx.x, j = blockIdx.x;
    const int* Hrow = Hm + (size_t)j * NB;
    for (int i = tid; i < NB; i += 256) cl[i] = boff[i] + Hrow[i];
    __syncthreads();
    int ebase = j * EPB;
#pragma unroll
    for (int i = 0; i < 3; ++i) {
        int e = ebase + tid + i * 256;
        if (e < N_EDGES) {
            int r = rows[e];
            int slot = atomicAdd(&cl[r >> 6], 1);
            int2 rec;
            rec.x = cols[e] | ((r & 63) << 16);
            rec.y = __float_as_int(vals[e]);
            erec[slot] = rec;
        }
    }
}

// ---------------- gather: block per bucket; LDS counting sort, REGISTER accumulate ----------------
// 512 threads (8 waves, 8 nodes/wave). Within a node, the two HALF-WAVES each
// process alternate edges: 32 lanes x ushort4 (8B) covers all 128 dims, so 2
// edges are in flight per unroll step; 4-deep unroll -> 8 loads in flight/wave.
// Final cross-half combine: one shfl_xor(32) per accumulator.
__global__ __launch_bounds__(512) void gather_kernel(const unsigned short* __restrict__ h,
                                                     const int2* __restrict__ erec,
                                                     const int* __restrict__ boff,
                                                     float* __restrict__ out) {
    __shared__ int2 srt[GCAP];            // 16 KB sorted records
    __shared__ int hist[64];
    __shared__ int cursor[64];
    __shared__ int starts[65];
    int tid = threadIdx.x, b = blockIdx.x;
    int beg = boff[b], end = boff[b + 1];
    int cnt = end - beg;
    int w = tid >> 6, lane = tid & 63;
    int pos = lane & 31;                  // dim group: dims pos*4 .. pos*4+3
    int half = lane >> 5;

    if (tid < 64) hist[tid] = 0;
    __syncthreads();

    if (cnt <= GCAP) {
        // ---- phase 1: stage to registers + 64-bin histogram (1 int LDS atomic/edge)
        int2 rec[4];
        int  rr[4];
#pragma unroll
        for (int k = 0; k < 4; ++k) {
            int i = tid + k * 512;
            if (i < cnt) {
                rec[k] = erec[beg + i];
                rr[k] = (rec[k].x >> 16) & 63;
                atomicAdd(&hist[rr[k]], 1);
            }
        }
        __syncthreads();
        // ---- phase 2: exclusive scan of the 64 bins (wave 0)
        if (tid < 64) {
            int v = hist[tid], incl = v;
#pragma unroll
            for (int d = 1; d < 64; d <<= 1) {
                int t = __shfl_up(incl, d);
                if (tid >= d) incl += t;
            }
            starts[tid] = incl - v;
            cursor[tid] = incl - v;
            if (tid == 63) starts[64] = incl;
        }
        __syncthreads();
        // ---- phase 3: place into sorted LDS order
#pragma unroll
        for (int k = 0; k < 4; ++k) {
            int i = tid + k * 512;
            if (i < cnt) {
                int pos2 = atomicAdd(&cursor[rr[k]], 1);
                srt[pos2] = rec[k];
            }
        }
        __syncthreads();
        // ---- phase 4: per-node register accumulation, 8 nodes per wave,
        //      half-wave edge interleave (stride 2), 4-deep unroll
        for (int t0 = 0; t0 < 8; ++t0) {
            int t = w * 8 + t0;
            int node = b * 64 + t;
            int s0 = starts[t], s1 = starts[t + 1];
            float a0 = 0.f, a1 = 0.f, a2 = 0.f, a3 = 0.f;
            int i = s0 + half;
            for (; i + 6 < s1; i += 8) {
                int2 r0 = srt[i], r1 = srt[i + 2], r2 = srt[i + 4], r3 = srt[i + 6];
                ushort4 h0 = *((const ushort4*)(h + (size_t)(r0.x & 0xFFFF) * DIM) + pos);
                ushort4 h1 = *((const ushort4*)(h + (size_t)(r1.x & 0xFFFF) * DIM) + pos);
                ushort4 h2 = *((const ushort4*)(h + (size_t)(r2.x & 0xFFFF) * DIM) + pos);
                ushort4 h3 = *((const ushort4*)(h + (size_t)(r3.x & 0xFFFF) * DIM) + pos);
                float v0 = __int_as_float(r0.y), v1 = __int_as_float(r1.y);
                float v2 = __int_as_float(r2.y), v3 = __int_as_float(r3.y);
                a0 += v0 * bf2f(h0.x) + v1 * bf2f(h1.x) + v2 * bf2f(h2.x) + v3 * bf2f(h3.x);
                a1 += v0 * bf2f(h0.y) + v1 * bf2f(h1.y) + v2 * bf2f(h2.y) + v3 * bf2f(h3.y);
                a2 += v0 * bf2f(h0.z) + v1 * bf2f(h1.z) + v2 * bf2f(h2.z) + v3 * bf2f(h3.z);
                a3 += v0 * bf2f(h0.w) + v1 * bf2f(h1.w) + v2 * bf2f(h2.w) + v3 * bf2f(h3.w);
            }
            for (; i < s1; i += 2) {
                int2 r0 = srt[i];
                ushort4 h0 = *((const ushort4*)(h + (size_t)(r0.x & 0xFFFF) * DIM) + pos);
                float v0 = __int_as_float(r0.y);
                a0 += v0 * bf2f(h0.x);
                a1 += v0 * bf2f(h0.y);
                a2 += v0 * bf2f(h0.z);
                a3 += v0 * bf2f(h0.w);
            }
            // combine the two halves
            a0 += __shfl_xor(a0, 32);
            a1 += __shfl_xor(a1, 32);
            a2 += __shfl_xor(a2, 32);
            a3 += __shfl_xor(a3, 32);
            if (half == 0 && node < N_NODES) {
                float4 o;
                o.x = fmaxf(a0, 0.f);
                o.y = fmaxf(a1, 0.f);
                o.z = fmaxf(a2, 0.f);
                o.w = fmaxf(a3, 0.f);
                *reinterpret_cast<float4*>(&out[(size_t)node * DIM + pos * 4]) = o;
            }
        }
    } else {
        // ---- oversize-bucket fallback (statistically unreachable, kept for correctness)
        for (int t0 = 0; t0 < 8; ++t0) {
            int t = w * 8 + t0;
            int node = b * 64 + t;
            float a0 = 0.f, a1 = 0.f, a2 = 0.f, a3 = 0.f;
            for (int i = half; i < cnt; i += 2) {
                int2 r = erec[beg + i];
                if (((r.x >> 16) & 63) == t) {
                    ushort4 hv = *((const ushort4*)(h + (size_t)(r.x & 0xFFFF) * DIM) + pos);
                    float v = __int_as_float(r.y);
                    a0 += v * bf2f(hv.x);
                    a1 += v * bf2f(hv.y);
                    a2 += v * bf2f(hv.z);
                    a3 += v * bf2f(hv.w);
                }
            }
            a0 += __shfl_xor(a0, 32);
            a1 += __shfl_xor(a1, 32);
            a2 += __shfl_xor(a2, 32);
            a3 += __shfl_xor(a3, 32);
            if (half == 0 && node < N_NODES) {
                float4 o;
                o.x = fmaxf(a0, 0.f);
                o.y = fmaxf(a1, 0.f);
                o.z = fmaxf(a2, 0.f);
                o.w = fmaxf(a3, 0.f);
                *reinterpret_cast<float4*>(&out[(size_t)node * DIM + pos * 4]) = o;
            }
        }
    }
}

// ---------------- fallback: atomic scatter over bf16 h ----------------
__global__ __launch_bounds__(256) void edge_kernel(const unsigned short* __restrict__ h,
                                                   const float* __restrict__ vals,
                                                   const int* __restrict__ rows,
                                                   const int* __restrict__ cols,
                                                   float* __restrict__ out) {
    long long gid = (long long)blockIdx.x * 256 + threadIdx.x;
    int e    = (int)(gid >> 5);
    int lane = (int)(gid & 31);
    if (e >= N_EDGES) return;
    int r = rows[e];
    int c = cols[e];
    float v = vals[e];
    ushort4 hv = *((const ushort4*)(h + (size_t)c * DIM) + lane);
    float* op = &out[(size_t)r * DIM + lane * 4];
    atomicAdd(op + 0, v * bf2f(hv.x));
    atomicAdd(op + 1, v * bf2f(hv.y));
    atomicAdd(op + 2, v * bf2f(hv.z));
    atomicAdd(op + 3, v * bf2f(hv.w));
}

__global__ __launch_bounds__(256) void relu_kernel(float* __restrict__ out) {
    int i = blockIdx.x * 256 + threadIdx.x;
    float4* p = reinterpret_cast<float4*>(out) + i;
    float4 v = *p;
    v.x = fmaxf(v.x, 0.f);
    v.y = fmaxf(v.y, 0.f);
    v.z = fmaxf(v.z, 0.f);
    v.w = fmaxf(v.w, 0.f);
    *p = v;
}

extern "C" void kernel_launch(void* const* d_in, const int* in_sizes, int n_in,
                              void* d_out, int out_size, void* d_ws, size_t ws_size,
                              hipStream_t stream) {
    const float* x    = (const float*)d_in[0];
    const float* W    = (const float*)d_in[1];
    const float* vals = (const float*)d_in[2];
    const int*   rows = (const int*)d_in[3];
    const int*   cols = (const int*)d_in[4];
    float* out = (float*)d_out;

    // ---- workspace layout ----
    unsigned short* h = (unsigned short*)d_ws;               // 12.8 MB bf16
    int2* erec = (int2*)(h + (size_t)N_NODES * DIM);         // 4.8 MB
    int*  Hm   = (int*)(erec + N_EDGES);                     // 2.45 MB
    int*  tot  = Hm + (size_t)NB * NB;                       // 782
    int*  boff = tot + NB;                                   // 783
    size_t need = (size_t)((char*)(boff + NB + 1) - (char*)d_ws);

    if (ws_size >= need) {
        // h = bf16(x @ W^T) via MFMA, bucket histogram fused (LDS-only atomics)
        gemm_kernel<<<GEMM_BLOCKS, 256, 0, stream>>>(x, W, h, rows, Hm);
        scanA_kernel<<<(NB * 64 + 255) / 256, 256, 0, stream>>>(Hm, tot);
        scanB_kernel<<<1, 1024, 0, stream>>>(tot, boff);
        scatter_kernel<<<NB, 256, 0, stream>>>(rows, cols, vals, Hm, boff, erec);
        gather_kernel<<<NB, 512, 0, stream>>>(h, erec, boff, out);
    } else {
        // fallback: atomic scatter path (needs only h)
        gemm_kernel<<<GEMM_BLOCKS, 256, 0, stream>>>(x, W, h, nullptr, nullptr);
        hipMemsetAsync(d_out, 0, (size_t)N_NODES * DIM * sizeof(float), stream);
        edge_kernel<<<(N_EDGES * 32) / 256, 256, 0, stream>>>(h, vals, rows, cols, out);
        relu_kernel<<<(N_NODES * DIM / 4) / 256, 256, 0, stream>>>(out);
    }
}